// Round 5
// baseline (704.671 us; speedup 1.0000x reference)
//
#include <hip/hip_runtime.h>
#include <hip/hip_cooperative_groups.h>
#include <cmath>
#include <cfloat>

namespace cg = cooperative_groups;

#define DEV __device__ __forceinline__

DEV unsigned enc_f(float x) { unsigned u = __float_as_uint(x); return (u >> 31) ? ~u : (u | 0x80000000u); }
DEV float dec_f(unsigned u) { return __uint_as_float((u >> 31) ? (u & 0x7FFFFFFFu) : ~u); }

// ---------------- encoder: z_q, cl = zq@Wl0_bot, crb = zq@Wr0_bot + b0 ----------------
__global__ __launch_bounds__(256) void encoder_kernel(
    const int* __restrict__ ids, const float* __restrict__ rssi,
    const float* __restrict__ emb, const float* __restrict__ ew, const float* __restrict__ eb,
    const float* __restrict__ Wl0, const float* __restrict__ Wr0, const float* __restrict__ b0,
    float* __restrict__ zout, int NQ)
{
    __shared__ float zsh[4][64];
    __shared__ float zq[64];
    int j = threadIdx.x & 63;
    int g = threadIdx.x >> 6;
    float acc = 0.f;
    for (int q = g; q < NQ; q += 4) {
        int id = ids[q];
        const float* e = emb + (size_t)id * 32;
        float p = eb[j];
#pragma unroll
        for (int k = 0; k < 32; ++k) p = fmaf(e[k], ew[k * 64 + j], p);
        p = fmaf(rssi[q], ew[32 * 64 + j], p);
        acc += fmaxf(p, 0.f);
    }
    zsh[g][j] = acc;
    __syncthreads();
    if (g == 0) {
        float z = (zsh[0][j] + zsh[1][j] + zsh[2][j] + zsh[3][j]) / (float)NQ;
        zq[j] = z;
        zout[j] = z;
    }
    __syncthreads();
    if (g == 0) {
        float cl = 0.f, cr = 0.f;
        for (int k = 0; k < 64; ++k) {
            float zk = zq[k];
            cl = fmaf(zk, Wl0[(128 + k) * 64 + j], cl);
            cr = fmaf(zk, Wr0[(128 + k) * 64 + j], cr);
        }
        zout[64 + j] = cl;
        zout[128 + j] = cr + b0[j];
    }
}

// ---------------- cooperative CSR build: count + scan + scatter in ONE dispatch ----------------
// 512 blocks x 256 thr (2 blocks/CU, trivially co-resident). XCD-partitioned scatter
// (part = blockIdx&7 owns 1/8 of nodes -> full-line srcs writebacks, see round-2 win).
__global__ __launch_bounds__(256) void csr_kernel(
    const int* __restrict__ src, const int* __restrict__ dst,
    int* __restrict__ deg, int* __restrict__ offs, int* __restrict__ cursor,
    int* __restrict__ bsum, int* __restrict__ bbase, int* __restrict__ srcs,
    int E, int N, int NB)
{
    cg::grid_group grid = cg::this_grid();
    __shared__ int sh[256];
    const int t = threadIdx.x;
    const int nblk = gridDim.x;

    // phase 1: degree count
    for (int i = blockIdx.x * 256 + t; i < E; i += nblk * 256)
        atomicAdd(&deg[dst[i]], 1);
    grid.sync();

    // phase 2: per-256-chunk local exclusive scan
    for (int c = blockIdx.x; c < NB; c += nblk) {
        int i = c * 256 + t;
        int v = (i < N) ? deg[i] : 0;
        sh[t] = v;
        __syncthreads();
        for (int d = 1; d < 256; d <<= 1) {
            int u = (t >= d) ? sh[t - d] : 0;
            __syncthreads();
            sh[t] += u;
            __syncthreads();
        }
        if (i < N) offs[i] = sh[t] - v;
        if (t == 255) bsum[c] = sh[255];
        __syncthreads();
    }
    grid.sync();

    // phase 3: scan chunk sums (block 0 only)
    if (blockIdx.x == 0) {
        int C = (NB + 255) >> 8;
        int c0 = t * C, c1 = min(c0 + C, NB);
        int s = 0;
        for (int i = c0; i < c1; ++i) s += bsum[i];
        sh[t] = s;
        __syncthreads();
        for (int d = 1; d < 256; d <<= 1) {
            int u = (t >= d) ? sh[t - d] : 0;
            __syncthreads();
            sh[t] += u;
            __syncthreads();
        }
        int run = (t > 0) ? sh[t - 1] : 0;
        for (int i = c0; i < c1; ++i) { bbase[i] = run; run += bsum[i]; }
        if (t == 255) offs[N] = sh[255];
    }
    grid.sync();

    // phase 4: add chunk base, init cursor
    for (int c = blockIdx.x; c < NB; c += nblk) {
        int i = c * 256 + t;
        if (i < N) {
            int o = offs[i] + bbase[c];
            offs[i] = o;
            cursor[i] = o;
        }
    }
    grid.sync();

    // phase 5: XCD-partitioned scatter
    {
        const int part = blockIdx.x & 7;
        const int npart = (N + 7) >> 3;
        const int lo = part * npart;
        const int hi = min(lo + npart, N);
        const int nchunk = (E + 4095) >> 12;
        for (int c = blockIdx.x >> 3; c < nchunk; c += (nblk >> 3)) {
            int base = c * 4096 + t;
#pragma unroll
            for (int it = 0; it < 16; ++it) {
                int i = base + it * 256;
                if (i < E) {
                    int d = dst[i];
                    if (d >= lo && d < hi) {
                        int p = atomicAdd(&cursor[d], 1);
                        srcs[p] = src[i];
                    }
                }
            }
        }
    }
}

// ---------------- layer-0 GEMM (K=128, dual out): O1 = x@B1, O2 = x@B2 + add2 ----------------
// A staged fully once (8 float4/thread); B chunked 32-k.
__global__ __launch_bounds__(256) void gemm0_kernel(
    const float* __restrict__ A, const float* __restrict__ B1, const float* __restrict__ B2,
    const float* __restrict__ add2,
    float* __restrict__ O1, float* __restrict__ O2, int N)
{
    constexpr int K = 128;
    __shared__ float As[K][68];     // 34.8 KB, [k][row]
    __shared__ float Bs[32][128];   // 16.4 KB

    const int tid = threadIdx.x;
    const int cg = tid & 31;
    const int rg = tid >> 5;
    const int row0 = blockIdx.x * 64;

    // stage all of A for this 64-row tile
#pragma unroll
    for (int i = 0; i < 8; ++i) {
        int vi = i * 256 + tid;
        int r = vi >> 5;
        int k4 = (vi & 31) << 2;
        int row = row0 + r;
        float4 v = make_float4(0.f, 0.f, 0.f, 0.f);
        if (row < N) v = *(const float4*)(A + (size_t)row * K + k4);
        As[k4 + 0][r] = v.x; As[k4 + 1][r] = v.y; As[k4 + 2][r] = v.z; As[k4 + 3][r] = v.w;
    }

    float acc[8][4];
#pragma unroll
    for (int i = 0; i < 8; ++i)
#pragma unroll
        for (int j = 0; j < 4; ++j) acc[i][j] = 0.f;

    for (int kc = 0; kc < K; kc += 32) {
#pragma unroll
        for (int i = 0; i < 4; ++i) {
            int vi = i * 256 + tid;
            int k = vi >> 5;
            int c = (vi & 31) << 2;
            const float* sp = (c < 64) ? (B1 + (size_t)(kc + k) * 64 + c)
                                       : (B2 + (size_t)(kc + k) * 64 + (c - 64));
            *(float4*)&Bs[k][c] = *(const float4*)sp;
        }
        __syncthreads();
#pragma unroll
        for (int k = 0; k < 32; ++k) {
            float4 a0 = *(const float4*)&As[kc + k][rg * 8];
            float4 a1 = *(const float4*)&As[kc + k][rg * 8 + 4];
            float a[8] = {a0.x, a0.y, a0.z, a0.w, a1.x, a1.y, a1.z, a1.w};
            float4 bv = *(const float4*)&Bs[k][cg * 4];
#pragma unroll
            for (int i = 0; i < 8; ++i) {
                acc[i][0] = fmaf(a[i], bv.x, acc[i][0]);
                acc[i][1] = fmaf(a[i], bv.y, acc[i][1]);
                acc[i][2] = fmaf(a[i], bv.z, acc[i][2]);
                acc[i][3] = fmaf(a[i], bv.w, acc[i][3]);
            }
        }
        __syncthreads();
    }

    int c0 = cg * 4;
    float* O; int c; const float* addp;
    if (c0 < 64) { O = O1; c = c0; addp = nullptr; }
    else         { O = O2; c = c0 - 64; addp = add2; }
    float4 av = make_float4(0.f, 0.f, 0.f, 0.f);
    if (addp) av = *(const float4*)(addp + c);
#pragma unroll
    for (int i = 0; i < 8; ++i) {
        int row = row0 + rg * 8 + i;
        if (row < N) {
            float4 o;
            o.x = acc[i][0] + av.x; o.y = acc[i][1] + av.y;
            o.z = acc[i][2] + av.z; o.w = acc[i][3] + av.w;
            *(float4*)(O + (size_t)row * 64 + c) = o;
        }
    }
}

// ---------------- K=64 dual GEMM, single-barrier full staging ----------------
__global__ __launch_bounds__(256) void gemm64_kernel(
    const float* __restrict__ A, const float* __restrict__ B1, const float* __restrict__ B2,
    const float* __restrict__ add2,
    float* __restrict__ O1, float* __restrict__ O2, int N)
{
    __shared__ float As[64][68];    // 17.4 KB
    __shared__ float Bs[64][128];   // 32.8 KB -> 50 KB total, 3 blocks/CU

    const int tid = threadIdx.x;
    const int cg = tid & 31;
    const int rg = tid >> 5;
    const int row0 = blockIdx.x * 64;

    // stage A (64x64) transposed
#pragma unroll
    for (int i = 0; i < 4; ++i) {
        int vi = i * 256 + tid;
        int r = vi >> 4;
        int k4 = (vi & 15) << 2;
        int row = row0 + r;
        float4 v = make_float4(0.f, 0.f, 0.f, 0.f);
        if (row < N) v = *(const float4*)(A + (size_t)row * 64 + k4);
        As[k4 + 0][r] = v.x; As[k4 + 1][r] = v.y; As[k4 + 2][r] = v.z; As[k4 + 3][r] = v.w;
    }
    // stage B (64x128: B1 | B2)
#pragma unroll
    for (int i = 0; i < 8; ++i) {
        int vi = i * 256 + tid;
        int k = vi >> 5;
        int c = (vi & 31) << 2;
        const float* sp = (c < 64) ? (B1 + (size_t)k * 64 + c)
                                   : (B2 + (size_t)k * 64 + (c - 64));
        *(float4*)&Bs[k][c] = *(const float4*)sp;
    }
    __syncthreads();

    float acc[8][4];
#pragma unroll
    for (int i = 0; i < 8; ++i)
#pragma unroll
        for (int j = 0; j < 4; ++j) acc[i][j] = 0.f;

#pragma unroll 8
    for (int k = 0; k < 64; ++k) {
        float4 a0 = *(const float4*)&As[k][rg * 8];
        float4 a1 = *(const float4*)&As[k][rg * 8 + 4];
        float a[8] = {a0.x, a0.y, a0.z, a0.w, a1.x, a1.y, a1.z, a1.w};
        float4 bv = *(const float4*)&Bs[k][cg * 4];
#pragma unroll
        for (int i = 0; i < 8; ++i) {
            acc[i][0] = fmaf(a[i], bv.x, acc[i][0]);
            acc[i][1] = fmaf(a[i], bv.y, acc[i][1]);
            acc[i][2] = fmaf(a[i], bv.z, acc[i][2]);
            acc[i][3] = fmaf(a[i], bv.w, acc[i][3]);
        }
    }

    int c0 = cg * 4;
    float* O; int c; const float* addp;
    if (c0 < 64) { O = O1; c = c0; addp = nullptr; }
    else         { O = O2; c = c0 - 64; addp = add2; }
    float4 av = make_float4(0.f, 0.f, 0.f, 0.f);
    if (addp) av = *(const float4*)(addp + c);
#pragma unroll
    for (int i = 0; i < 8; ++i) {
        int row = row0 + rg * 8 + i;
        if (row < N) {
            float4 o;
            o.x = acc[i][0] + av.x; o.y = acc[i][1] + av.y;
            o.z = acc[i][2] + av.z; o.w = acc[i][3] + av.w;
            *(float4*)(O + (size_t)row * 64 + c) = o;
        }
    }
}

// ---------------- aggregation: h = relu(segsum(m)/clip(deg,1) + [deg>0]*cl + r) ----------------
// wave per node, 64 lanes = 64 features, up to 16 gathers in flight (at L3-BW floor)
__global__ __launch_bounds__(256) void agg_kernel(
    const float* __restrict__ m, const float* __restrict__ r,
    const int* __restrict__ off, const int* __restrict__ srcs,
    const float* __restrict__ cl, float* __restrict__ hout, int N)
{
    int node = blockIdx.x * 4 + threadIdx.y;
    if (node >= N) return;
    int lane = threadIdx.x;
    int e0 = off[node], e1 = off[node + 1];
    float a[16];
#pragma unroll
    for (int i = 0; i < 16; ++i) a[i] = 0.f;

    for (int base = e0; base < e1; base += 64) {
        int e = base + lane;
        int sv = (e < e1) ? srcs[e] : 0;
        int cnt = min(e1 - base, 64);
        int j = 0;
        for (; j + 16 <= cnt; j += 16) {
#pragma unroll
            for (int u = 0; u < 16; ++u) {
                int s = __shfl(sv, j + u);
                a[u] += m[(size_t)s * 64 + lane];
            }
        }
        for (; j + 4 <= cnt; j += 4) {
#pragma unroll
            for (int u = 0; u < 4; ++u) {
                int s = __shfl(sv, j + u);
                a[u] += m[(size_t)s * 64 + lane];
            }
        }
        for (; j < cnt; ++j) {
            int s = __shfl(sv, j);
            a[0] += m[(size_t)s * 64 + lane];
        }
    }
    float sum = 0.f;
#pragma unroll
    for (int i = 0; i < 16; ++i) sum += a[i];
    int deg = e1 - e0;
    float v = sum / (float)(deg > 0 ? deg : 1) + r[(size_t)node * 64 + lane];
    if (cl != nullptr && deg > 0) v += cl[lane];
    hout[(size_t)node * 64 + lane] = fmaxf(v, 0.f);
}

// ---------------- fused scorer: s = relu(h@w1+b1)@w2 + b2, block max -> atomicMax ----------------
__global__ __launch_bounds__(256) void scorer_gemm_kernel(
    const float* __restrict__ A, const float* __restrict__ B1,
    const float* __restrict__ bias, const float* __restrict__ w2, const float* __restrict__ b2,
    float* __restrict__ sbuf, unsigned* __restrict__ red, int N)
{
    __shared__ float As[64][68];
    __shared__ float Bs[64][64];
    __shared__ float smax[256];

    const int tid = threadIdx.x;
    const int cg = tid & 31;
    const int rg = tid >> 5;
    const int row0 = blockIdx.x * 64;

#pragma unroll
    for (int i = 0; i < 4; ++i) {
        int vi = i * 256 + tid;
        int r = vi >> 4;
        int k4 = (vi & 15) << 2;
        int row = row0 + r;
        float4 v = make_float4(0.f, 0.f, 0.f, 0.f);
        if (row < N) v = *(const float4*)(A + (size_t)row * 64 + k4);
        As[k4 + 0][r] = v.x; As[k4 + 1][r] = v.y; As[k4 + 2][r] = v.z; As[k4 + 3][r] = v.w;
    }
#pragma unroll
    for (int i = 0; i < 4; ++i) {
        int vi = i * 256 + tid;
        int k = vi >> 4;
        int c = (vi & 15) << 2;
        *(float4*)&Bs[k][c] = *(const float4*)(B1 + (size_t)k * 64 + c);
    }
    __syncthreads();

    float acc[8][2];
#pragma unroll
    for (int i = 0; i < 8; ++i) { acc[i][0] = 0.f; acc[i][1] = 0.f; }

#pragma unroll 8
    for (int k = 0; k < 64; ++k) {
        float4 a0 = *(const float4*)&As[k][rg * 8];
        float4 a1 = *(const float4*)&As[k][rg * 8 + 4];
        float a[8] = {a0.x, a0.y, a0.z, a0.w, a1.x, a1.y, a1.z, a1.w};
        float2 bv = *(const float2*)&Bs[k][cg * 2];
#pragma unroll
        for (int i = 0; i < 8; ++i) {
            acc[i][0] = fmaf(a[i], bv.x, acc[i][0]);
            acc[i][1] = fmaf(a[i], bv.y, acc[i][1]);
        }
    }

    float2 av = *(const float2*)(bias + cg * 2);
    float w0 = w2[cg * 2], w1 = w2[cg * 2 + 1];
    float bb = b2[0];
    float svals[8];
#pragma unroll
    for (int i = 0; i < 8; ++i) {
        float t0 = fmaxf(acc[i][0] + av.x, 0.f);
        float t1 = fmaxf(acc[i][1] + av.y, 0.f);
        float p = fmaf(t0, w0, t1 * w1);
#pragma unroll
        for (int d = 16; d >= 1; d >>= 1) p += __shfl_xor(p, d, 64);
        svals[i] = p;
    }
    float smx = -FLT_MAX;
    if (cg == 0) {
#pragma unroll
        for (int i = 0; i < 8; ++i) {
            int row = row0 + rg * 8 + i;
            if (row < N) {
                float s = svals[i] + bb;
                sbuf[row] = s;
                smx = fmaxf(smx, s);
            }
        }
    }
    smax[tid] = smx;
    __syncthreads();
    for (int d = 128; d >= 1; d >>= 1) {
        if (tid < d) smax[tid] = fmaxf(smax[tid], smax[tid + d]);
        __syncthreads();
    }
    if (tid == 0) atomicMax(red, enc_f(smax[0]));
}

// ---------------- cooperative softmax: sum-reduce, grid sync, normalize ----------------
__global__ __launch_bounds__(256) void softmax_kernel(
    const float* __restrict__ s, const float* __restrict__ pos,
    unsigned* __restrict__ redu, float* __restrict__ out, int N)
{
    cg::grid_group grid = cg::this_grid();
    float* redf = (float*)redu;
    float mx = dec_f(redu[0]);
    float se = 0.f, px = 0.f, py = 0.f;
    for (int i = blockIdx.x * 256 + threadIdx.x; i < N; i += gridDim.x * 256) {
        float e = expf(s[i] - mx);
        se += e;
        px = fmaf(e, pos[2 * i], px);
        py = fmaf(e, pos[2 * i + 1], py);
    }
#pragma unroll
    for (int d = 32; d >= 1; d >>= 1) {
        se += __shfl_xor(se, d, 64);
        px += __shfl_xor(px, d, 64);
        py += __shfl_xor(py, d, 64);
    }
    if ((threadIdx.x & 63) == 0) {
        atomicAdd(&redf[1], se);
        atomicAdd(&redf[2], px);
        atomicAdd(&redf[3], py);
    }
    grid.sync();
    float S = redf[1];
    for (int i = blockIdx.x * 256 + threadIdx.x; i < N; i += gridDim.x * 256)
        out[2 + i] = expf(s[i] - mx) / S;
    if (blockIdx.x == 0 && threadIdx.x == 0) {
        out[0] = redf[2] / S;
        out[1] = redf[3] / S;
    }
}

extern "C" void kernel_launch(void* const* d_in, const int* in_sizes, int n_in,
                              void* d_out, int out_size, void* d_ws, size_t ws_size,
                              hipStream_t stream)
{
    const float* x    = (const float*)d_in[0];
    const float* pos  = (const float*)d_in[1];
    const int*   ei   = (const int*)d_in[2];
    const int*   qids = (const int*)d_in[3];
    const float* qrs  = (const float*)d_in[4];
    const float* emb  = (const float*)d_in[5];
    const float* ew   = (const float*)d_in[6];
    const float* eb   = (const float*)d_in[7];
    const float* Wl0  = (const float*)d_in[8];
    const float* Wr0  = (const float*)d_in[9];
    const float* b0   = (const float*)d_in[10];
    const float* Wl1  = (const float*)d_in[11];
    const float* Wr1  = (const float*)d_in[12];
    const float* b1   = (const float*)d_in[13];
    const float* Wl2  = (const float*)d_in[14];
    const float* Wr2  = (const float*)d_in[15];
    const float* b2   = (const float*)d_in[16];
    const float* sw1  = (const float*)d_in[17];
    const float* sb1  = (const float*)d_in[18];
    const float* sw2  = (const float*)d_in[19];
    const float* sb2  = (const float*)d_in[20];

    const int N  = in_sizes[0] / 128;
    const int E  = in_sizes[2] / 2;
    const int NQ = in_sizes[3];
    const int NB = (N + 255) / 256;

    char* base = (char*)d_ws;
    size_t wsoff = 0;
    auto take = [&](size_t bytes) -> char* {
        char* p = base + wsoff;
        wsoff = (wsoff + bytes + 255) & ~(size_t)255;
        return p;
    };
    int*      deg    = (int*)take((size_t)N * 4);
    int*      offs   = (int*)take((size_t)(N + 1) * 4);
    int*      cursor = (int*)take((size_t)N * 4);
    int*      bsum   = (int*)take((size_t)NB * 4);
    int*      bbase  = (int*)take((size_t)NB * 4);
    int*      srcs   = (int*)take((size_t)E * 4);
    float*    zout   = (float*)take(192 * 4);   // zq[64], cl[64], crb[64]
    unsigned* red    = (unsigned*)take(16);     // [0]=max(enc) [1]=sumexp [2]=px [3]=py
    float*    mbuf   = (float*)take((size_t)N * 64 * 4);
    float*    rbuf   = (float*)take((size_t)N * 64 * 4);
    float*    hbuf   = (float*)take((size_t)N * 64 * 4);
    float*    sbuf   = (float*)take((size_t)N * 4);
    (void)ws_size; (void)n_in; (void)out_size;

    const int* esrc = ei;
    const int* edst = ei + E;

    hipMemsetAsync(deg, 0, (size_t)N * 4, stream);
    hipMemsetAsync(red, 0, 16, stream);

    encoder_kernel<<<1, 256, 0, stream>>>(qids, qrs, emb, ew, eb, Wl0, Wr0, b0, zout, NQ);

    // cooperative CSR build (count + scan + scatter)
    {
        int Ea = E, Na = N, NBa = NB;
        void* cargs[] = { (void*)&esrc, (void*)&edst, (void*)&deg, (void*)&offs, (void*)&cursor,
                          (void*)&bsum, (void*)&bbase, (void*)&srcs, (void*)&Ea, (void*)&Na, (void*)&NBa };
        hipLaunchCooperativeKernel((void*)csr_kernel, dim3(512), dim3(256), cargs, 0, stream);
    }

    int gblocks = (N + 63) / 64;
    dim3 ablk(64, 4);
    int ablocks = (N + 3) / 4;

    // layer 0: mbuf = x@Wl0_top, rbuf = x@Wr0_top + (zq@Wr0_bot + b0)
    gemm0_kernel<<<gblocks, 256, 0, stream>>>(x, Wl0, Wr0, zout + 128, mbuf, rbuf, N);
    agg_kernel<<<ablocks, ablk, 0, stream>>>(mbuf, rbuf, offs, srcs, zout + 64, hbuf, N);
    // layer 1
    gemm64_kernel<<<gblocks, 256, 0, stream>>>(hbuf, Wl1, Wr1, b1, mbuf, rbuf, N);
    agg_kernel<<<ablocks, ablk, 0, stream>>>(mbuf, rbuf, offs, srcs, nullptr, hbuf, N);
    // layer 2
    gemm64_kernel<<<gblocks, 256, 0, stream>>>(hbuf, Wl2, Wr2, b2, mbuf, rbuf, N);
    agg_kernel<<<ablocks, ablk, 0, stream>>>(mbuf, rbuf, offs, srcs, nullptr, hbuf, N);
    // fused scorer (writes sbuf + atomicMax into red[0])
    scorer_gemm_kernel<<<gblocks, 256, 0, stream>>>(hbuf, sw1, sb1, sw2, sb2, sbuf, red, N);

    // cooperative softmax (sum + normalize)
    {
        int Na = N;
        float* outp = (float*)d_out;
        void* sargs[] = { (void*)&sbuf, (void*)&pos, (void*)&red, (void*)&outp, (void*)&Na };
        hipLaunchCooperativeKernel((void*)softmax_kernel, dim3(256), dim3(256), sargs, 0, stream);
    }
}

// Round 6
// 405.246 us; speedup vs baseline: 1.7389x; 1.7389x over previous
//
#include <hip/hip_runtime.h>
#include <cmath>
#include <cfloat>

#define DEV __device__ __forceinline__

DEV unsigned enc_f(float x) { unsigned u = __float_as_uint(x); return (u >> 31) ? ~u : (u | 0x80000000u); }
DEV float dec_f(unsigned u) { return __uint_as_float((u >> 31) ? (u & 0x7FFFFFFFu) : ~u); }

// ---------------- encoder (last block) + degree count (all other blocks) ----------------
// Independent work merged into one dispatch: blocks [0, nCount) grid-stride the edge list
// counting degrees; block nCount runs the 256-thread encoder producing
// zout = { z_q[64], cl = zq@Wl0_bot [64], crb = zq@Wr0_bot + b0 [64] }.
__global__ __launch_bounds__(256) void enc_count_kernel(
    const int* __restrict__ dst, int* __restrict__ deg, int E, int nCount,
    const int* __restrict__ ids, const float* __restrict__ rssi,
    const float* __restrict__ emb, const float* __restrict__ ew, const float* __restrict__ eb,
    const float* __restrict__ Wl0, const float* __restrict__ Wr0, const float* __restrict__ b0,
    float* __restrict__ zout, int NQ)
{
    if (blockIdx.x < (unsigned)nCount) {
        int i = blockIdx.x * 256 + threadIdx.x;
        if (i < E) atomicAdd(&deg[dst[i]], 1);
        return;
    }
    // encoder block
    __shared__ float zsh[4][64];
    __shared__ float zq[64];
    int j = threadIdx.x & 63;
    int g = threadIdx.x >> 6;
    float acc = 0.f;
    for (int q = g; q < NQ; q += 4) {
        int id = ids[q];
        const float* e = emb + (size_t)id * 32;
        float p = eb[j];
#pragma unroll
        for (int k = 0; k < 32; ++k) p = fmaf(e[k], ew[k * 64 + j], p);
        p = fmaf(rssi[q], ew[32 * 64 + j], p);
        acc += fmaxf(p, 0.f);
    }
    zsh[g][j] = acc;
    __syncthreads();
    if (g == 0) {
        float z = (zsh[0][j] + zsh[1][j] + zsh[2][j] + zsh[3][j]) / (float)NQ;
        zq[j] = z;
        zout[j] = z;
    }
    __syncthreads();
    if (g == 0) {
        float cl = 0.f, cr = 0.f;
        for (int k = 0; k < 64; ++k) {
            float zk = zq[k];
            cl = fmaf(zk, Wl0[(128 + k) * 64 + j], cl);
            cr = fmaf(zk, Wr0[(128 + k) * 64 + j], cr);
        }
        zout[64 + j] = cl;
        zout[128 + j] = cr + b0[j];
    }
}

// ---------------- CSR build: multi-block scan ----------------
__global__ __launch_bounds__(256) void scanA_kernel(const int* __restrict__ deg, int* __restrict__ offs,
                                                    int* __restrict__ bsum, int N)
{
    __shared__ int sh[256];
    int t = threadIdx.x;
    int i = blockIdx.x * 256 + t;
    int v = (i < N) ? deg[i] : 0;
    sh[t] = v;
    __syncthreads();
#pragma unroll
    for (int d = 1; d < 256; d <<= 1) {
        int u = (t >= d) ? sh[t - d] : 0;
        __syncthreads();
        sh[t] += u;
        __syncthreads();
    }
    if (i < N) offs[i] = sh[t] - v;
    if (t == 255) bsum[blockIdx.x] = sh[255];
}

__global__ __launch_bounds__(256) void scanB_kernel(const int* __restrict__ bsum, int* __restrict__ bbase,
                                                    int* __restrict__ offs, int NB, int N)
{
    __shared__ int sh[256];
    int t = threadIdx.x;
    int C = (NB + 255) >> 8;
    int c0 = t * C, c1 = min(c0 + C, NB);
    int s = 0;
    for (int i = c0; i < c1; ++i) s += bsum[i];
    sh[t] = s;
    __syncthreads();
#pragma unroll
    for (int d = 1; d < 256; d <<= 1) {
        int u = (t >= d) ? sh[t - d] : 0;
        __syncthreads();
        sh[t] += u;
        __syncthreads();
    }
    int run = (t > 0) ? sh[t - 1] : 0;
    for (int i = c0; i < c1; ++i) { bbase[i] = run; run += bsum[i]; }
    if (t == 255) offs[N] = sh[255];
}

__global__ __launch_bounds__(256) void scanC_kernel(int* __restrict__ offs, int* __restrict__ cursor,
                                                    const int* __restrict__ bbase, int N)
{
    int i = blockIdx.x * 256 + threadIdx.x;
    if (i < N) {
        int o = offs[i] + bbase[blockIdx.x];
        offs[i] = o;
        cursor[i] = o;
    }
}

// XCD-partitioned scatter: part = blockIdx&7 owns 1/8 of the node range -> each srcs
// region written by one XCD only -> full-line writebacks (round-2 win: 52us -> ~15us).
__global__ __launch_bounds__(256) void scatter_kernel(const int* __restrict__ src, const int* __restrict__ dst,
                                                      int* __restrict__ cursor, int* __restrict__ srcs,
                                                      int E, int N)
{
    const int part = blockIdx.x & 7;
    const int chunk = blockIdx.x >> 3;
    const int npart = (N + 7) >> 3;
    const int lo = part * npart;
    const int hi = min(lo + npart, N);
    const int base = chunk * 4096 + threadIdx.x;
#pragma unroll
    for (int it = 0; it < 16; ++it) {
        int i = base + it * 256;
        if (i < E) {
            int d = dst[i];
            if (d >= lo && d < hi) {
                int p = atomicAdd(&cursor[d], 1);
                srcs[p] = src[i];
            }
        }
    }
}

// ---------------- layer-0 GEMM (K=128, dual out): O1 = x@B1, O2 = x@B2 + add2 ----------------
__global__ __launch_bounds__(256) void gemm0_kernel(
    const float* __restrict__ A, const float* __restrict__ B1, const float* __restrict__ B2,
    const float* __restrict__ add2,
    float* __restrict__ O1, float* __restrict__ O2, int N)
{
    constexpr int K = 128;
    __shared__ float As[K][68];     // 34.8 KB, [k][row]
    __shared__ float Bs[32][128];   // 16.4 KB -> 51 KB total, 3 blocks/CU

    const int tid = threadIdx.x;
    const int cg = tid & 31;
    const int rg = tid >> 5;
    const int row0 = blockIdx.x * 64;

#pragma unroll
    for (int i = 0; i < 8; ++i) {
        int vi = i * 256 + tid;
        int r = vi >> 5;
        int k4 = (vi & 31) << 2;
        int row = row0 + r;
        float4 v = make_float4(0.f, 0.f, 0.f, 0.f);
        if (row < N) v = *(const float4*)(A + (size_t)row * K + k4);
        As[k4 + 0][r] = v.x; As[k4 + 1][r] = v.y; As[k4 + 2][r] = v.z; As[k4 + 3][r] = v.w;
    }

    float acc[8][4];
#pragma unroll
    for (int i = 0; i < 8; ++i)
#pragma unroll
        for (int j = 0; j < 4; ++j) acc[i][j] = 0.f;

    for (int kc = 0; kc < K; kc += 32) {
#pragma unroll
        for (int i = 0; i < 4; ++i) {
            int vi = i * 256 + tid;
            int k = vi >> 5;
            int c = (vi & 31) << 2;
            const float* sp = (c < 64) ? (B1 + (size_t)(kc + k) * 64 + c)
                                       : (B2 + (size_t)(kc + k) * 64 + (c - 64));
            *(float4*)&Bs[k][c] = *(const float4*)sp;
        }
        __syncthreads();
#pragma unroll
        for (int k = 0; k < 32; ++k) {
            float4 a0 = *(const float4*)&As[kc + k][rg * 8];
            float4 a1 = *(const float4*)&As[kc + k][rg * 8 + 4];
            float a[8] = {a0.x, a0.y, a0.z, a0.w, a1.x, a1.y, a1.z, a1.w};
            float4 bv = *(const float4*)&Bs[k][cg * 4];
#pragma unroll
            for (int i = 0; i < 8; ++i) {
                acc[i][0] = fmaf(a[i], bv.x, acc[i][0]);
                acc[i][1] = fmaf(a[i], bv.y, acc[i][1]);
                acc[i][2] = fmaf(a[i], bv.z, acc[i][2]);
                acc[i][3] = fmaf(a[i], bv.w, acc[i][3]);
            }
        }
        __syncthreads();
    }

    int c0 = cg * 4;
    float* O; int c; const float* addp;
    if (c0 < 64) { O = O1; c = c0; addp = nullptr; }
    else         { O = O2; c = c0 - 64; addp = add2; }
    float4 av = make_float4(0.f, 0.f, 0.f, 0.f);
    if (addp) av = *(const float4*)(addp + c);
#pragma unroll
    for (int i = 0; i < 8; ++i) {
        int row = row0 + rg * 8 + i;
        if (row < N) {
            float4 o;
            o.x = acc[i][0] + av.x; o.y = acc[i][1] + av.y;
            o.z = acc[i][2] + av.z; o.w = acc[i][3] + av.w;
            *(float4*)(O + (size_t)row * 64 + c) = o;
        }
    }
}

// ---------------- K=64 dual GEMM, single-barrier full staging ----------------
__global__ __launch_bounds__(256) void gemm64_kernel(
    const float* __restrict__ A, const float* __restrict__ B1, const float* __restrict__ B2,
    const float* __restrict__ add2,
    float* __restrict__ O1, float* __restrict__ O2, int N)
{
    __shared__ float As[64][68];    // 17.4 KB
    __shared__ float Bs[64][128];   // 32.8 KB -> 50 KB, 3 blocks/CU

    const int tid = threadIdx.x;
    const int cg = tid & 31;
    const int rg = tid >> 5;
    const int row0 = blockIdx.x * 64;

#pragma unroll
    for (int i = 0; i < 4; ++i) {
        int vi = i * 256 + tid;
        int r = vi >> 4;
        int k4 = (vi & 15) << 2;
        int row = row0 + r;
        float4 v = make_float4(0.f, 0.f, 0.f, 0.f);
        if (row < N) v = *(const float4*)(A + (size_t)row * 64 + k4);
        As[k4 + 0][r] = v.x; As[k4 + 1][r] = v.y; As[k4 + 2][r] = v.z; As[k4 + 3][r] = v.w;
    }
#pragma unroll
    for (int i = 0; i < 8; ++i) {
        int vi = i * 256 + tid;
        int k = vi >> 5;
        int c = (vi & 31) << 2;
        const float* sp = (c < 64) ? (B1 + (size_t)k * 64 + c)
                                   : (B2 + (size_t)k * 64 + (c - 64));
        *(float4*)&Bs[k][c] = *(const float4*)sp;
    }
    __syncthreads();

    float acc[8][4];
#pragma unroll
    for (int i = 0; i < 8; ++i)
#pragma unroll
        for (int j = 0; j < 4; ++j) acc[i][j] = 0.f;

#pragma unroll 8
    for (int k = 0; k < 64; ++k) {
        float4 a0 = *(const float4*)&As[k][rg * 8];
        float4 a1 = *(const float4*)&As[k][rg * 8 + 4];
        float a[8] = {a0.x, a0.y, a0.z, a0.w, a1.x, a1.y, a1.z, a1.w};
        float4 bv = *(const float4*)&Bs[k][cg * 4];
#pragma unroll
        for (int i = 0; i < 8; ++i) {
            acc[i][0] = fmaf(a[i], bv.x, acc[i][0]);
            acc[i][1] = fmaf(a[i], bv.y, acc[i][1]);
            acc[i][2] = fmaf(a[i], bv.z, acc[i][2]);
            acc[i][3] = fmaf(a[i], bv.w, acc[i][3]);
        }
    }

    int c0 = cg * 4;
    float* O; int c; const float* addp;
    if (c0 < 64) { O = O1; c = c0; addp = nullptr; }
    else         { O = O2; c = c0 - 64; addp = add2; }
    float4 av = make_float4(0.f, 0.f, 0.f, 0.f);
    if (addp) av = *(const float4*)(addp + c);
#pragma unroll
    for (int i = 0; i < 8; ++i) {
        int row = row0 + rg * 8 + i;
        if (row < N) {
            float4 o;
            o.x = acc[i][0] + av.x; o.y = acc[i][1] + av.y;
            o.z = acc[i][2] + av.z; o.w = acc[i][3] + av.w;
            *(float4*)(O + (size_t)row * 64 + c) = o;
        }
    }
}

// ---------------- aggregation: h = relu(segsum(m)/clip(deg,1) + [deg>0]*cl + r) ----------------
// wave per node, 64 lanes = 64 features, 16 gathers in flight. At the compulsory-miss
// floor: ~86MB L2-miss traffic/dispatch at ~2 TB/s (each XCD touches ~86% of m's rows).
__global__ __launch_bounds__(256) void agg_kernel(
    const float* __restrict__ m, const float* __restrict__ r,
    const int* __restrict__ off, const int* __restrict__ srcs,
    const float* __restrict__ cl, float* __restrict__ hout, int N)
{
    int node = blockIdx.x * 4 + threadIdx.y;
    if (node >= N) return;
    int lane = threadIdx.x;
    int e0 = off[node], e1 = off[node + 1];
    float a[16];
#pragma unroll
    for (int i = 0; i < 16; ++i) a[i] = 0.f;

    for (int base = e0; base < e1; base += 64) {
        int e = base + lane;
        int sv = (e < e1) ? srcs[e] : 0;
        int cnt = min(e1 - base, 64);
        int j = 0;
        for (; j + 16 <= cnt; j += 16) {
#pragma unroll
            for (int u = 0; u < 16; ++u) {
                int s = __shfl(sv, j + u);
                a[u] += m[(size_t)s * 64 + lane];
            }
        }
        for (; j + 4 <= cnt; j += 4) {
#pragma unroll
            for (int u = 0; u < 4; ++u) {
                int s = __shfl(sv, j + u);
                a[u] += m[(size_t)s * 64 + lane];
            }
        }
        for (; j < cnt; ++j) {
            int s = __shfl(sv, j);
            a[0] += m[(size_t)s * 64 + lane];
        }
    }
    float sum = 0.f;
#pragma unroll
    for (int i = 0; i < 16; ++i) sum += a[i];
    int deg = e1 - e0;
    float v = sum / (float)(deg > 0 ? deg : 1) + r[(size_t)node * 64 + lane];
    if (cl != nullptr && deg > 0) v += cl[lane];
    hout[(size_t)node * 64 + lane] = fmaxf(v, 0.f);
}

// ---------------- fused scorer: s = relu(h@w1+b1)@w2 + b2, block max -> atomicMax ----------------
__global__ __launch_bounds__(256) void scorer_gemm_kernel(
    const float* __restrict__ A, const float* __restrict__ B1,
    const float* __restrict__ bias, const float* __restrict__ w2, const float* __restrict__ b2,
    float* __restrict__ sbuf, unsigned* __restrict__ red, int N)
{
    __shared__ float As[64][68];
    __shared__ float Bs[64][64];
    __shared__ float smax[256];

    const int tid = threadIdx.x;
    const int cg = tid & 31;
    const int rg = tid >> 5;
    const int row0 = blockIdx.x * 64;

#pragma unroll
    for (int i = 0; i < 4; ++i) {
        int vi = i * 256 + tid;
        int r = vi >> 4;
        int k4 = (vi & 15) << 2;
        int row = row0 + r;
        float4 v = make_float4(0.f, 0.f, 0.f, 0.f);
        if (row < N) v = *(const float4*)(A + (size_t)row * 64 + k4);
        As[k4 + 0][r] = v.x; As[k4 + 1][r] = v.y; As[k4 + 2][r] = v.z; As[k4 + 3][r] = v.w;
    }
#pragma unroll
    for (int i = 0; i < 4; ++i) {
        int vi = i * 256 + tid;
        int k = vi >> 4;
        int c = (vi & 15) << 2;
        *(float4*)&Bs[k][c] = *(const float4*)(B1 + (size_t)k * 64 + c);
    }
    __syncthreads();

    float acc[8][2];
#pragma unroll
    for (int i = 0; i < 8; ++i) { acc[i][0] = 0.f; acc[i][1] = 0.f; }

#pragma unroll 8
    for (int k = 0; k < 64; ++k) {
        float4 a0 = *(const float4*)&As[k][rg * 8];
        float4 a1 = *(const float4*)&As[k][rg * 8 + 4];
        float a[8] = {a0.x, a0.y, a0.z, a0.w, a1.x, a1.y, a1.z, a1.w};
        float2 bv = *(const float2*)&Bs[k][cg * 2];
#pragma unroll
        for (int i = 0; i < 8; ++i) {
            acc[i][0] = fmaf(a[i], bv.x, acc[i][0]);
            acc[i][1] = fmaf(a[i], bv.y, acc[i][1]);
        }
    }

    float2 av = *(const float2*)(bias + cg * 2);
    float w0 = w2[cg * 2], w1 = w2[cg * 2 + 1];
    float bb = b2[0];
    float svals[8];
#pragma unroll
    for (int i = 0; i < 8; ++i) {
        float t0 = fmaxf(acc[i][0] + av.x, 0.f);
        float t1 = fmaxf(acc[i][1] + av.y, 0.f);
        float p = fmaf(t0, w0, t1 * w1);
#pragma unroll
        for (int d = 16; d >= 1; d >>= 1) p += __shfl_xor(p, d, 64);
        svals[i] = p;
    }
    float smx = -FLT_MAX;
    if (cg == 0) {
#pragma unroll
        for (int i = 0; i < 8; ++i) {
            int row = row0 + rg * 8 + i;
            if (row < N) {
                float s = svals[i] + bb;
                sbuf[row] = s;
                smx = fmaxf(smx, s);
            }
        }
    }
    smax[tid] = smx;
    __syncthreads();
    for (int d = 128; d >= 1; d >>= 1) {
        if (tid < d) smax[tid] = fmaxf(smax[tid], smax[tid + d]);
        __syncthreads();
    }
    if (tid == 0) atomicMax(red, enc_f(smax[0]));
}

// ---------------- softmax reductions ----------------
__global__ __launch_bounds__(256) void sum_kernel(const float* __restrict__ s, const float* __restrict__ pos,
                                                  const unsigned* __restrict__ redmax, float* __restrict__ red, int N)
{
    float mx = dec_f(redmax[0]);
    float se = 0.f, px = 0.f, py = 0.f;
    for (int i = blockIdx.x * blockDim.x + threadIdx.x; i < N; i += gridDim.x * blockDim.x) {
        float e = expf(s[i] - mx);
        se += e;
        px = fmaf(e, pos[2 * i], px);
        py = fmaf(e, pos[2 * i + 1], py);
    }
#pragma unroll
    for (int d = 32; d >= 1; d >>= 1) {
        se += __shfl_xor(se, d, 64);
        px += __shfl_xor(px, d, 64);
        py += __shfl_xor(py, d, 64);
    }
    if ((threadIdx.x & 63) == 0) {
        atomicAdd(&red[1], se);
        atomicAdd(&red[2], px);
        atomicAdd(&red[3], py);
    }
}

__global__ __launch_bounds__(256) void final_kernel(const float* __restrict__ s, const unsigned* __restrict__ redmax,
                                                    const float* __restrict__ red, float* __restrict__ out, int N)
{
    float mx = dec_f(redmax[0]);
    float S = red[1];
    int i = blockIdx.x * blockDim.x + threadIdx.x;
    if (i < N) out[2 + i] = expf(s[i] - mx) / S;
    if (i == 0) {
        out[0] = red[2] / S;
        out[1] = red[3] / S;
    }
}

extern "C" void kernel_launch(void* const* d_in, const int* in_sizes, int n_in,
                              void* d_out, int out_size, void* d_ws, size_t ws_size,
                              hipStream_t stream)
{
    const float* x    = (const float*)d_in[0];
    const float* pos  = (const float*)d_in[1];
    const int*   ei   = (const int*)d_in[2];
    const int*   qids = (const int*)d_in[3];
    const float* qrs  = (const float*)d_in[4];
    const float* emb  = (const float*)d_in[5];
    const float* ew   = (const float*)d_in[6];
    const float* eb   = (const float*)d_in[7];
    const float* Wl0  = (const float*)d_in[8];
    const float* Wr0  = (const float*)d_in[9];
    const float* b0   = (const float*)d_in[10];
    const float* Wl1  = (const float*)d_in[11];
    const float* Wr1  = (const float*)d_in[12];
    const float* b1   = (const float*)d_in[13];
    const float* Wl2  = (const float*)d_in[14];
    const float* Wr2  = (const float*)d_in[15];
    const float* b2   = (const float*)d_in[16];
    const float* sw1  = (const float*)d_in[17];
    const float* sb1  = (const float*)d_in[18];
    const float* sw2  = (const float*)d_in[19];
    const float* sb2  = (const float*)d_in[20];

    const int N  = in_sizes[0] / 128;
    const int E  = in_sizes[2] / 2;
    const int NQ = in_sizes[3];
    const int NB = (N + 255) / 256;

    char* base = (char*)d_ws;
    size_t wsoff = 0;
    auto take = [&](size_t bytes) -> char* {
        char* p = base + wsoff;
        wsoff = (wsoff + bytes + 255) & ~(size_t)255;
        return p;
    };
    int*      deg    = (int*)take((size_t)N * 4);
    int*      offs   = (int*)take((size_t)(N + 1) * 4);
    int*      cursor = (int*)take((size_t)N * 4);
    int*      bsum   = (int*)take((size_t)NB * 4);
    int*      bbase  = (int*)take((size_t)NB * 4);
    int*      srcs   = (int*)take((size_t)E * 4);
    float*    zout   = (float*)take(192 * 4);   // zq[64], cl[64], crb[64]
    unsigned* red    = (unsigned*)take(16);     // [0]=max(enc) [1]=sumexp [2]=px [3]=py
    float*    mbuf   = (float*)take((size_t)N * 64 * 4);
    float*    rbuf   = (float*)take((size_t)N * 64 * 4);
    float*    hbuf   = (float*)take((size_t)N * 64 * 4);
    float*    sbuf   = (float*)take((size_t)N * 4);
    (void)ws_size; (void)n_in; (void)out_size;

    const int* esrc = ei;
    const int* edst = ei + E;

    hipMemsetAsync(deg, 0, (size_t)N * 4, stream);
    hipMemsetAsync(red, 0, 16, stream);

    // encoder merged into count: blocks [0,nCount) count degrees, block nCount = encoder
    int nCount = (E + 255) / 256;
    enc_count_kernel<<<nCount + 1, 256, 0, stream>>>(edst, deg, E, nCount,
                                                     qids, qrs, emb, ew, eb, Wl0, Wr0, b0, zout, NQ);
    scanA_kernel<<<NB, 256, 0, stream>>>(deg, offs, bsum, N);
    scanB_kernel<<<1, 256, 0, stream>>>(bsum, bbase, offs, NB, N);
    scanC_kernel<<<NB, 256, 0, stream>>>(offs, cursor, bbase, N);
    int schunks = (E + 4095) / 4096;
    scatter_kernel<<<schunks * 8, 256, 0, stream>>>(esrc, edst, cursor, srcs, E, N);

    int gblocks = (N + 63) / 64;
    dim3 ablk(64, 4);
    int ablocks = (N + 3) / 4;

    // layer 0: mbuf = x@Wl0_top, rbuf = x@Wr0_top + (zq@Wr0_bot + b0)
    gemm0_kernel<<<gblocks, 256, 0, stream>>>(x, Wl0, Wr0, zout + 128, mbuf, rbuf, N);
    agg_kernel<<<ablocks, ablk, 0, stream>>>(mbuf, rbuf, offs, srcs, zout + 64, hbuf, N);
    // layer 1
    gemm64_kernel<<<gblocks, 256, 0, stream>>>(hbuf, Wl1, Wr1, b1, mbuf, rbuf, N);
    agg_kernel<<<ablocks, ablk, 0, stream>>>(mbuf, rbuf, offs, srcs, nullptr, hbuf, N);
    // layer 2
    gemm64_kernel<<<gblocks, 256, 0, stream>>>(hbuf, Wl2, Wr2, b2, mbuf, rbuf, N);
    agg_kernel<<<ablocks, ablk, 0, stream>>>(mbuf, rbuf, offs, srcs, nullptr, hbuf, N);
    // fused scorer (writes sbuf + atomicMax into red[0])
    scorer_gemm_kernel<<<gblocks, 256, 0, stream>>>(hbuf, sw1, sb1, sw2, sb2, sbuf, red, N);

    sum_kernel<<<128, 256, 0, stream>>>(sbuf, pos, red, (float*)red, N);
    final_kernel<<<(N + 255) / 256, 256, 0, stream>>>(sbuf, red, (float*)red, (float*)d_out, N);
}